// Round 4
// baseline (508.378 us; speedup 1.0000x reference)
//
#include <hip/hip_runtime.h>
#include <hip/hip_bf16.h>

// Problem constants (fixed by reference setup_inputs).
#define T_TOTAL 2048
#define BATCH   128
#define NIN     256
#define NOUT    128

// Decomposition: T-chunks x B-chunks x NIN-halves -> 512 blocks, 2/CU.
#define TC      256                 // timesteps per block
#define BC      4                   // batches per block
#define WARM    32                  // warm-up steps (0.5^32 ~ 2e-10 truncation)
#define NTC     (T_TOTAL / TC)      // 8
#define NBC     (BATCH / BC)        // 32
#define NTB     (NTC * NBC)         // 256 (t,b) tiles
#define NBLOCKS (NTB * 2)           // 512 blocks (x2 NIN halves) = 2 blocks/CU
#define SUP     16                  // t-steps per supergroup -> K = SUP*BC = 64
#define NSUP    (TC / SUP)          // 16 barriers per block

#define OUT_ELEMS  (NOUT * NIN)     // 32768
#define SLOT_ELEMS (NOUT * 128)     // 16384 per-block partial (128 o x 128 i)

typedef __attribute__((ext_vector_type(8)))  __bf16 bf16x8;
typedef __attribute__((ext_vector_type(2)))  __bf16 bf16x2;
typedef __attribute__((ext_vector_type(16))) float  f32x16;
typedef __attribute__((ext_vector_type(4)))  unsigned uint32x4;

// packed f32x2 -> bf16x2 (RTNE)
static __device__ __forceinline__ unsigned pack_bf16(float a, float b) {
    bf16x2 v = { (__bf16)a, (__bf16)b };
    union { bf16x2 v; unsigned u; } c; c.v = v; return c.u;
}

// Fused STDP, 2 blocks/CU. Wave specialization:
//   waves 0-3: fp32 trace scan (2 batch chains) + stage B (trace) to LDS
//   waves 4-7: load out-spikes + stage A to LDS
//   all waves: MFMA (2 32x32 tiles each, acc = 32 VGPRs)
// K-map per supergroup: kk = s16*16 + bpair*8 + q*2 + delta  (q = t mod 4).
// LDS rows = 128 B (64 bf16 k), XOR-swizzled 16-B chunks -> b128 R/W.
__global__ __launch_bounds__(512, 4)
void stdp_main(const float* __restrict__ in, const float* __restrict__ outs,
               float* __restrict__ dst, int nslots, int use_atomic)
{
    __shared__ __align__(16) unsigned tr_lds[2][128 * 32];   // 32 KB, B (trace, n=i)
    __shared__ __align__(16) unsigned ot_lds[2][128 * 32];   // 32 KB, A (spikes, m=o)

    const int tid = threadIdx.x;
    const int tb  = blockIdx.x & 255;    // (tc,bc) tile
    const int ih  = blockIdx.x >> 8;     // NIN half; high bit -> pair shares XCD
    const int bc  = tb & 31;
    const int tc  = tb >> 5;
    const int b0  = bc * BC;
    const int t0  = tc * TC;
    const int ibase = ih * 128;

    const int wv   = tid >> 6;           // 8 waves
    const bool isB = (wv < 4);           // waves 0-3: trace producer
    const int r7   = tid & 127;          // i7 (B role) or o7 (A role)
    const int bp   = (tid >> 7) & 1;     // batch pair within role group

    const int lane  = tid & 63;
    const int l31   = lane & 31;
    const int khalf = lane >> 5;
    const int mt    = wv & 3;            // m-tile (o rows mt*32..+31)
    const int ntb2  = (wv >> 2) * 2;     // n-tile base (2 tiles per wave)

    float tr0 = 0.f, tr1 = 0.f;

    // ---- warm-up: trace scan only (B waves) ----
    if (isB && tc > 0) {
        for (int t = t0 - WARM; t < t0; t += 8) {
            float v0[8], v1[8];
#pragma unroll
            for (int u = 0; u < 8; ++u) {
                const size_t base = ((size_t)(t + u) * BATCH + b0 + 2 * bp) * NIN + ibase + r7;
                v0[u] = in[base];
                v1[u] = in[base + NIN];
            }
#pragma unroll
            for (int u = 0; u < 8; ++u) {
                tr0 = 0.5f * tr0 + v0[u];
                tr1 = 0.5f * tr1 + v1[u];
            }
        }
    }

    f32x16 acc[2];
    acc[0] = (f32x16)(0.f);
    acc[1] = (f32x16)(0.f);

    for (int sg = 0; sg < NSUP; ++sg) {
        const int ts  = t0 + sg * SUP;
        const int buf = sg & 1;

        if (isB) {
            // ---- load full supergroup (2 chains x 16 t), scan, stage B ----
            float v0[SUP], v1[SUP];
#pragma unroll
            for (int s = 0; s < SUP; ++s) {
                const size_t base = ((size_t)(ts + s) * BATCH + b0 + 2 * bp) * NIN + ibase + r7;
                v0[s] = in[base];
                v1[s] = in[base + NIN];
            }
#pragma unroll
            for (int s16 = 0; s16 < 4; ++s16) {
                unsigned w[4];
#pragma unroll
                for (int q = 0; q < 4; ++q) {
                    const int s = s16 * 4 + q;
                    tr0 = 0.5f * tr0 + v0[s];
                    tr1 = 0.5f * tr1 + v1[s];
                    w[q] = pack_bf16(tr0, tr1);
                }
                const int p = (s16 * 2 + bp) ^ (r7 & 7);
                *(uint32x4*)&tr_lds[buf][r7 * 32 + p * 4] = (uint32x4){w[0], w[1], w[2], w[3]};
            }
        } else {
            // ---- load out-spikes (2 batches x 16 t), stage A ----
            float v0[SUP], v1[SUP];
#pragma unroll
            for (int s = 0; s < SUP; ++s) {
                const size_t base = ((size_t)(ts + s) * BATCH + b0 + 2 * bp) * NOUT + r7;
                v0[s] = outs[base];
                v1[s] = outs[base + NOUT];
            }
#pragma unroll
            for (int s16 = 0; s16 < 4; ++s16) {
                unsigned w[4];
#pragma unroll
                for (int q = 0; q < 4; ++q) {
                    const int s = s16 * 4 + q;
                    w[q] = pack_bf16(v0[s], v1[s]);
                }
                const int p = (s16 * 2 + bp) ^ (r7 & 7);
                *(uint32x4*)&ot_lds[buf][r7 * 32 + p * 4] = (uint32x4){w[0], w[1], w[2], w[3]};
            }
        }

        __syncthreads();   // one barrier per supergroup (double-buffered LDS)

        // ---- 8 MFMAs per wave: 4 sub-k blocks x 2 n-tiles ----
#pragma unroll
        for (int s16 = 0; s16 < 4; ++s16) {
            const int pc = (s16 * 2 + khalf) ^ (l31 & 7);
            const bf16x8 a = *(const bf16x8*)&ot_lds[buf][(mt * 32 + l31) * 32 + pc * 4];
#pragma unroll
            for (int j = 0; j < 2; ++j) {
                const bf16x8 b = *(const bf16x8*)&tr_lds[buf][((ntb2 + j) * 32 + l31) * 32 + pc * 4];
                acc[j] = __builtin_amdgcn_mfma_f32_32x32x16_bf16(a, b, acc[j], 0, 0, 0);
            }
        }
    }

    // ---- epilogue: D[row,col] -> partial[o = mt*32+row][i7 = (ntb2+j)*32+col] ----
    if (use_atomic) {
        float* base = dst + (size_t)(blockIdx.x % nslots) * OUT_ELEMS;
#pragma unroll
        for (int j = 0; j < 2; ++j) {
            const int icol = ibase + (ntb2 + j) * 32 + l31;
#pragma unroll
            for (int r = 0; r < 16; ++r) {
                const int row = (r & 3) + 8 * (r >> 2) + 4 * khalf;
                atomicAdd(&base[(mt * 32 + row) * NIN + icol], acc[j][r]);
            }
        }
    } else {
        float* base = dst + (size_t)blockIdx.x * SLOT_ELEMS;
#pragma unroll
        for (int j = 0; j < 2; ++j) {
            const int icol = (ntb2 + j) * 32 + l31;
#pragma unroll
            for (int r = 0; r < 16; ++r) {
                const int row = (r & 3) + 8 * (r >> 2) + 4 * khalf;
                base[(mt * 32 + row) * 128 + icol] = acc[j][r];
            }
        }
    }
}

__global__ void zero_kernel(float* p, int n) {
    int i = blockIdx.x * blockDim.x + threadIdx.x;
    if (i < n) p[i] = 0.f;
}

// Sum 256 (t,b)-tile partials per output element; slot = ih*256 + tb.
__global__ __launch_bounds__(256)
void reduce_kernel(const float* __restrict__ ws, float* __restrict__ outp) {
    const int idx = blockIdx.x * 256 + threadIdx.x;   // o*256 + i
    const int i  = idx & 255;
    const int o  = idx >> 8;
    const int ih = i >> 7;
    const int i7 = i & 127;
    const size_t off = (size_t)(ih * 256) * SLOT_ELEMS + o * 128 + i7;
    float s = 0.f;
    for (int k = 0; k < 256; k += 16) {
        float v[16];
#pragma unroll
        for (int u = 0; u < 16; ++u) v[u] = ws[off + (size_t)(k + u) * SLOT_ELEMS];
#pragma unroll
        for (int u = 0; u < 16; ++u) s += v[u];
    }
    outp[idx] = s;
}

// Fallback reduce over nslots full-size atomic slots.
__global__ __launch_bounds__(256)
void reduce_slots_kernel(const float* __restrict__ ws, float* __restrict__ outp, int nslots) {
    const int idx = blockIdx.x * 256 + threadIdx.x;
    float s = 0.f;
    for (int k = 0; k < nslots; ++k) s += ws[(size_t)k * OUT_ELEMS + idx];
    outp[idx] = s;
}

extern "C" void kernel_launch(void* const* d_in, const int* in_sizes, int n_in,
                              void* d_out, int out_size, void* d_ws, size_t ws_size,
                              hipStream_t stream) {
    const float* in   = (const float*)d_in[0];
    const float* outs = (const float*)d_in[1];
    float* out = (float*)d_out;
    float* ws  = (float*)d_ws;

    if (ws_size >= (size_t)NBLOCKS * SLOT_ELEMS * sizeof(float)) {
        // plain per-block partials + reduce (preferred; 32 MB ws)
        stdp_main<<<NBLOCKS, 512, 0, stream>>>(in, outs, ws, NBLOCKS, 0);
        reduce_kernel<<<OUT_ELEMS / 256, 256, 0, stream>>>(ws, out);
    } else if (ws_size >= 16 * (size_t)OUT_ELEMS * sizeof(float)) {
        // 16 shared full-size slots, atomic accumulation
        zero_kernel<<<(16 * OUT_ELEMS + 255) / 256, 256, 0, stream>>>(ws, 16 * OUT_ELEMS);
        stdp_main<<<NBLOCKS, 512, 0, stream>>>(in, outs, ws, 16, 1);
        reduce_slots_kernel<<<OUT_ELEMS / 256, 256, 0, stream>>>(ws, out, 16);
    } else {
        // last resort: atomics straight into d_out
        zero_kernel<<<(OUT_ELEMS + 255) / 256, 256, 0, stream>>>(out, OUT_ELEMS);
        stdp_main<<<NBLOCKS, 512, 0, stream>>>(in, outs, out, 1, 1);
    }
}

// Round 5
// 478.489 us; speedup vs baseline: 1.0625x; 1.0625x over previous
//
#include <hip/hip_runtime.h>
#include <hip/hip_bf16.h>

// Problem constants (fixed by reference setup_inputs).
#define T_TOTAL 2048
#define BATCH   128
#define NIN     256
#define NOUT    128

// Barrier-free decomposition: block = (batch-pair, T-chunk), 8 waves = 8 n-tiles.
// Each lane owns one (i, d) trace chain in registers; the MFMA B-fragment
// (B[i=l31][k=kh*8+j], k = d*8 + t_local) is exactly the lane's own 8 scanned
// values -> NO LDS, NO __syncthreads, no collective vmcnt(0) drain ever.
#define TC      256                 // timesteps per block
#define NTC     (T_TOTAL / TC)      // 8
#define BC      2                   // batch pair per block
#define NBP     (BATCH / BC)        // 64
#define NBLOCKS (NBP * NTC)         // 512
#define WARM    32                  // warm-up steps (0.5^32 ~ 2e-10 truncation)
#define CT      8                   // timesteps per k-chunk (K = CT*BC = 16)
#define NCH     (TC / CT)           // 32 chunks per block

#define STRI    (BATCH * NIN)       // 32768 floats per timestep (in)
#define STRO    (BATCH * NOUT)     // 16384 floats per timestep (outs)
#define OUT_ELEMS (NOUT * NIN)      // 32768

typedef __attribute__((ext_vector_type(8)))  __bf16 bf16x8;
typedef __attribute__((ext_vector_type(2)))  __bf16 bf16x2;
typedef __attribute__((ext_vector_type(16))) float  f32x16;

// packed f32x2 -> bf16x2 (RTNE)
static __device__ __forceinline__ unsigned pack_bf16(float a, float b) {
    bf16x2 v = { (__bf16)a, (__bf16)b };
    union { bf16x2 v; unsigned u; } c; c.v = v; return c.u;
}
static __device__ __forceinline__ bf16x8 frag4(unsigned w0, unsigned w1,
                                               unsigned w2, unsigned w3) {
    union { unsigned u[4]; bf16x8 f; } c;
    c.u[0] = w0; c.u[1] = w1; c.u[2] = w2; c.u[3] = w3; return c.f;
}

__global__ __launch_bounds__(512, 2)   // <=256 VGPR: keep MLP in registers
void stdp_main(const float* __restrict__ in, const float* __restrict__ outs,
               float* __restrict__ dst, int use_atomic)
{
    const int tid  = threadIdx.x;
    const int lane = tid & 63;
    const int l31  = lane & 31;
    const int kh   = lane >> 5;          // batch-in-pair d (also MFMA k-half)
    const int nt   = tid >> 6;           // wave index = n-tile (i block)

    const int tc = blockIdx.x & 7;       // consecutive blocks spread T across XCDs
    const int bp = blockIdx.x >> 3;
    const int b0 = bp * BC;
    const int t0 = tc * TC;

    // per-lane invariant address parts
    const size_t in_off = (size_t)(b0 + kh) * NIN + nt * 32 + l31;
    const size_t ot_off = (size_t)(b0 + kh) * NOUT + l31;

    float tr = 0.f;

    // ---- warm-up: private trace scan, no output ----
    if (tc > 0) {
        for (int t = t0 - WARM; t < t0; t += 8) {
            float v[8];
#pragma unroll
            for (int u = 0; u < 8; ++u) v[u] = in[(size_t)(t + u) * STRI + in_off];
#pragma unroll
            for (int u = 0; u < 8; ++u) tr = 0.5f * tr + v[u];
        }
    }

    f32x16 acc[4];
#pragma unroll
    for (int m = 0; m < 4; ++m) acc[m] = (f32x16)(0.f);

    // prologue: in-values for chunk 0
    float cin[8];
#pragma unroll
    for (int j = 0; j < 8; ++j) cin[j] = in[(size_t)(t0 + j) * STRI + in_off];

    for (int c = 0; c < NCH; ++c) {
        const int tb = t0 + c * CT;

        // A-operand loads: out-spikes in frag layout (4 m-tiles x 8 t), 2x128B/instr.
        // All 8 waves read the same 8 KB window -> L1 broadcast.
        float af[4][8];
#pragma unroll
        for (int m = 0; m < 4; ++m)
#pragma unroll
            for (int j = 0; j < 8; ++j)
                af[m][j] = outs[(size_t)(tb + j) * STRO + ot_off + m * 32];

        // prefetch next chunk's in-values (keeps the chain loads deep in flight)
        float nin[8];
        if (c + 1 < NCH) {
#pragma unroll
            for (int j = 0; j < 8; ++j) nin[j] = in[(size_t)(tb + CT + j) * STRI + in_off];
        }

        // trace recurrence (exact fp32) -> B-fragment (lane's own 8 k-values)
        unsigned bw[4];
#pragma unroll
        for (int p = 0; p < 4; ++p) {
            tr = 0.5f * tr + cin[2 * p];
            const float f0 = tr;
            tr = 0.5f * tr + cin[2 * p + 1];
            bw[p] = pack_bf16(f0, tr);
        }
        const bf16x8 bfrag = frag4(bw[0], bw[1], bw[2], bw[3]);

        // 4 MFMAs: one per m-tile, k = d*8 + t_local
#pragma unroll
        for (int m = 0; m < 4; ++m) {
            const bf16x8 afrag = frag4(pack_bf16(af[m][0], af[m][1]),
                                       pack_bf16(af[m][2], af[m][3]),
                                       pack_bf16(af[m][4], af[m][5]),
                                       pack_bf16(af[m][6], af[m][7]));
            acc[m] = __builtin_amdgcn_mfma_f32_32x32x16_bf16(afrag, bfrag, acc[m], 0, 0, 0);
        }

#pragma unroll
        for (int j = 0; j < 8; ++j) cin[j] = nin[j];
    }

    // ---- epilogue: D col = lane&31 -> i, row = (r&3)+8*(r>>2)+4*kh -> o ----
    if (use_atomic) {
#pragma unroll
        for (int m = 0; m < 4; ++m) {
            const int icol = nt * 32 + l31;
#pragma unroll
            for (int r = 0; r < 16; ++r) {
                const int row = (r & 3) + 8 * (r >> 2) + 4 * kh;
                atomicAdd(&dst[(m * 32 + row) * NIN + icol], acc[m][r]);
            }
        }
    } else {
        float* base = dst + (size_t)blockIdx.x * OUT_ELEMS;
#pragma unroll
        for (int m = 0; m < 4; ++m) {
            const int icol = nt * 32 + l31;
#pragma unroll
            for (int r = 0; r < 16; ++r) {
                const int row = (r & 3) + 8 * (r >> 2) + 4 * kh;
                base[(m * 32 + row) * NIN + icol] = acc[m][r];
            }
        }
    }
}

__global__ void zero_kernel(float* p, int n) {
    int i = blockIdx.x * blockDim.x + threadIdx.x;
    if (i < n) p[i] = 0.f;
}

// Sum the 512 per-block partials.
__global__ __launch_bounds__(256)
void reduce_kernel(const float* __restrict__ ws, float* __restrict__ outp) {
    const int idx = blockIdx.x * 256 + threadIdx.x;
    float s = 0.f;
    for (int k = 0; k < NBLOCKS; k += 16) {
        float v[16];
#pragma unroll
        for (int u = 0; u < 16; ++u) v[u] = ws[(size_t)(k + u) * OUT_ELEMS + idx];
#pragma unroll
        for (int u = 0; u < 16; ++u) s += v[u];
    }
    outp[idx] = s;
}

extern "C" void kernel_launch(void* const* d_in, const int* in_sizes, int n_in,
                              void* d_out, int out_size, void* d_ws, size_t ws_size,
                              hipStream_t stream) {
    const float* in   = (const float*)d_in[0];
    const float* outs = (const float*)d_in[1];
    float* out = (float*)d_out;
    float* ws  = (float*)d_ws;

    if (ws_size >= (size_t)NBLOCKS * OUT_ELEMS * sizeof(float)) {
        // per-block partials (64 MB ws) + reduce
        stdp_main<<<NBLOCKS, 512, 0, stream>>>(in, outs, ws, 0);
        reduce_kernel<<<OUT_ELEMS / 256, 256, 0, stream>>>(ws, out);
    } else {
        // fallback: fp32 atomics straight into d_out
        zero_kernel<<<(OUT_ELEMS + 255) / 256, 256, 0, stream>>>(out, OUT_ELEMS);
        stdp_main<<<NBLOCKS, 512, 0, stream>>>(in, outs, out, 1);
    }
}

// Round 6
// 477.528 us; speedup vs baseline: 1.0646x; 1.0020x over previous
//
#include <hip/hip_runtime.h>
#include <hip/hip_bf16.h>

// Problem constants (fixed by reference setup_inputs).
#define T_TOTAL 2048
#define BATCH   128
#define NIN     256
#define NOUT    128

// Barrier-free, LDS-free decomposition. Block = (batch-pair, T-chunk),
// 1024 threads = 16 waves. Wave = (n-tile nt 0-7, m-half mh 0-1) -> 2 m-tiles,
// acc = 32 VGPRs. Each lane owns one (i, d) trace chain in registers; the
// MFMA B-fragment (B[i=l31][k=kh*8+j], k = d*8 + t_local) is exactly the
// lane's own 8 scanned values. All operands double-buffered in registers:
// everything consumed was loaded >= 1 chunk earlier. No __syncthreads ever.
// 256 blocks = 1 block/CU; launch_bounds(1024,4) -> 16 waves/CU, VGPR <= 128.
#define TC      512                 // timesteps per block
#define NTC     (T_TOTAL / TC)      // 4
#define BC      2                   // batch pair per block
#define NBP     (BATCH / BC)        // 64
#define NBLOCKS (NBP * NTC)         // 256
#define WARM    32                  // warm-up steps (0.5^32 ~ 2e-10 truncation)
#define CT      8                   // timesteps per k-chunk (K = CT*BC = 16)
#define NCH     (TC / CT)           // 64 chunks per block

#define STRI    (BATCH * NIN)       // 32768 floats per timestep (in)
#define STRO    (BATCH * NOUT)      // 16384 floats per timestep (outs)
#define OUT_ELEMS (NOUT * NIN)      // 32768

typedef __attribute__((ext_vector_type(8)))  __bf16 bf16x8;
typedef __attribute__((ext_vector_type(2)))  __bf16 bf16x2;
typedef __attribute__((ext_vector_type(16))) float  f32x16;

// packed f32x2 -> bf16x2 (RTNE)
static __device__ __forceinline__ unsigned pack_bf16(float a, float b) {
    bf16x2 v = { (__bf16)a, (__bf16)b };
    union { bf16x2 v; unsigned u; } c; c.v = v; return c.u;
}
static __device__ __forceinline__ bf16x8 frag4(unsigned w0, unsigned w1,
                                               unsigned w2, unsigned w3) {
    union { unsigned u[4]; bf16x8 f; } c;
    c.u[0] = w0; c.u[1] = w1; c.u[2] = w2; c.u[3] = w3; return c.f;
}

__global__ __launch_bounds__(1024, 4)
void stdp_main(const float* __restrict__ in, const float* __restrict__ outs,
               float* __restrict__ dst, int use_atomic)
{
    const int tid  = threadIdx.x;
    const int lane = tid & 63;
    const int l31  = lane & 31;
    const int kh   = lane >> 5;          // batch-in-pair d (also MFMA k-half)
    const int wv   = tid >> 6;           // 16 waves
    const int nt   = wv & 7;             // n-tile (i block)
    const int mh   = wv >> 3;            // m-half (o 0-63 / 64-127)

    const int tc = blockIdx.x & 3;       // consecutive blocks spread T across XCDs
    const int bp = blockIdx.x >> 2;
    const int b0 = bp * BC;
    const int t0 = tc * TC;

    // per-lane invariant address parts
    const size_t in_off = (size_t)(b0 + kh) * NIN + nt * 32 + l31;
    const size_t ot_off = (size_t)(b0 + kh) * NOUT + mh * 64 + l31;

    float tr = 0.f;

    // ---- warm-up: private trace scan, no output ----
    if (tc > 0) {
        for (int t = t0 - WARM; t < t0; t += 8) {
            float v[8];
#pragma unroll
            for (int u = 0; u < 8; ++u) v[u] = in[(size_t)(t + u) * STRI + in_off];
#pragma unroll
            for (int u = 0; u < 8; ++u) tr = 0.5f * tr + v[u];
        }
    }

    f32x16 acc[2];
    acc[0] = (f32x16)(0.f);
    acc[1] = (f32x16)(0.f);

    // double-buffered register operands
    float cin[2][8];        // in-values (trace feed)
    float af[2][2][8];      // out-spike A-operand values [buf][mm][t_local]

    // prologue: chunk 0 loads into buffer 0
#pragma unroll
    for (int j = 0; j < 8; ++j) cin[0][j] = in[(size_t)(t0 + j) * STRI + in_off];
#pragma unroll
    for (int mm = 0; mm < 2; ++mm)
#pragma unroll
        for (int j = 0; j < 8; ++j)
            af[0][mm][j] = outs[(size_t)(t0 + j) * STRO + ot_off + mm * 32];

    auto body = [&](int cur, int c) {
        const int tb  = t0 + c * CT;
        const int nxt = cur ^ 1;

        // prefetch next chunk into the other buffer (>= 1 chunk of slack)
        if (c + 1 < NCH) {
#pragma unroll
            for (int j = 0; j < 8; ++j)
                cin[nxt][j] = in[(size_t)(tb + CT + j) * STRI + in_off];
#pragma unroll
            for (int mm = 0; mm < 2; ++mm)
#pragma unroll
                for (int j = 0; j < 8; ++j)
                    af[nxt][mm][j] = outs[(size_t)(tb + CT + j) * STRO + ot_off + mm * 32];
        }

        // trace recurrence (exact fp32) -> B-fragment (lane's own 8 k-values)
        unsigned bw[4];
#pragma unroll
        for (int p = 0; p < 4; ++p) {
            tr = 0.5f * tr + cin[cur][2 * p];
            const float f0 = tr;
            tr = 0.5f * tr + cin[cur][2 * p + 1];
            bw[p] = pack_bf16(f0, tr);
        }
        const bf16x8 bfrag = frag4(bw[0], bw[1], bw[2], bw[3]);

        // 2 MFMAs: one per m-tile, k = d*8 + t_local
#pragma unroll
        for (int mm = 0; mm < 2; ++mm) {
            const bf16x8 afrag = frag4(pack_bf16(af[cur][mm][0], af[cur][mm][1]),
                                       pack_bf16(af[cur][mm][2], af[cur][mm][3]),
                                       pack_bf16(af[cur][mm][4], af[cur][mm][5]),
                                       pack_bf16(af[cur][mm][6], af[cur][mm][7]));
            acc[mm] = __builtin_amdgcn_mfma_f32_32x32x16_bf16(afrag, bfrag, acc[mm], 0, 0, 0);
        }
    };

    for (int cc = 0; cc < NCH; cc += 2) {
        body(0, cc);
        body(1, cc + 1);
    }

    // ---- epilogue: D col = l31 -> i, row = (r&3)+8*(r>>2)+4*kh -> o ----
    const int icol = nt * 32 + l31;
    if (use_atomic) {
#pragma unroll
        for (int mm = 0; mm < 2; ++mm)
#pragma unroll
            for (int r = 0; r < 16; ++r) {
                const int row = (r & 3) + 8 * (r >> 2) + 4 * kh;
                const int o   = mh * 64 + mm * 32 + row;
                atomicAdd(&dst[o * NIN + icol], acc[mm][r]);
            }
    } else {
        float* base = dst + (size_t)blockIdx.x * OUT_ELEMS;
#pragma unroll
        for (int mm = 0; mm < 2; ++mm)
#pragma unroll
            for (int r = 0; r < 16; ++r) {
                const int row = (r & 3) + 8 * (r >> 2) + 4 * kh;
                const int o   = mh * 64 + mm * 32 + row;
                base[o * NIN + icol] = acc[mm][r];
            }
    }
}

__global__ void zero_kernel(float* p, int n) {
    int i = blockIdx.x * blockDim.x + threadIdx.x;
    if (i < n) p[i] = 0.f;
}

// Sum the 256 per-block partials.
__global__ __launch_bounds__(256)
void reduce_kernel(const float* __restrict__ ws, float* __restrict__ outp) {
    const int idx = blockIdx.x * 256 + threadIdx.x;
    float s = 0.f;
    for (int k = 0; k < NBLOCKS; k += 16) {
        float v[16];
#pragma unroll
        for (int u = 0; u < 16; ++u) v[u] = ws[(size_t)(k + u) * OUT_ELEMS + idx];
#pragma unroll
        for (int u = 0; u < 16; ++u) s += v[u];
    }
    outp[idx] = s;
}

extern "C" void kernel_launch(void* const* d_in, const int* in_sizes, int n_in,
                              void* d_out, int out_size, void* d_ws, size_t ws_size,
                              hipStream_t stream) {
    const float* in   = (const float*)d_in[0];
    const float* outs = (const float*)d_in[1];
    float* out = (float*)d_out;
    float* ws  = (float*)d_ws;

    if (ws_size >= (size_t)NBLOCKS * OUT_ELEMS * sizeof(float)) {
        // per-block partials (32 MB ws) + reduce
        stdp_main<<<NBLOCKS, 1024, 0, stream>>>(in, outs, ws, 0);
        reduce_kernel<<<OUT_ELEMS / 256, 256, 0, stream>>>(ws, out);
    } else {
        // fallback: fp32 atomics straight into d_out
        zero_kernel<<<(OUT_ELEMS + 255) / 256, 256, 0, stream>>>(out, OUT_ELEMS);
        stdp_main<<<NBLOCKS, 1024, 0, stream>>>(in, outs, out, 1);
    }
}